// Round 1
// baseline (676.584 us; speedup 1.0000x reference)
//
#include <hip/hip_runtime.h>
#include <math.h>

// Problem dims
#define S_LEN 2048
#define D_HEAD 64
#define BH 32  // BS*H = 2*16

typedef __attribute__((ext_vector_type(8))) short short8;   // 8 x bf16 bits
typedef __attribute__((ext_vector_type(4))) float f32x4;

__device__ __forceinline__ short f2bf(float f) {
  union { float f; unsigned u; } a; a.f = f;
  unsigned u = a.u;
  unsigned r = (u + 0x7fffu + ((u >> 16) & 1u)) >> 16;   // RNE, inputs never NaN
  return (short)r;
}

// ---------------------------------------------------------------------------
// Kernel 0: transpose K [bh][64][2048] -> kT [bh][2048][64] (bf16)
//           transpose V [bh][2048][64] -> vT [bh][64][2048] (bf16)
// Gives 16B/lane contiguous MFMA-operand loads in the hot kernels.
// ---------------------------------------------------------------------------
__global__ __launch_bounds__(256) void transpose_kernel(
    const float* __restrict__ kin, const float* __restrict__ vin,
    unsigned short* __restrict__ kT, unsigned short* __restrict__ vT)
{
  __shared__ float tile[64][65];   // +1 pad: 2-way max on both phases (free)
  const int bh = blockIdx.y;
  const int bx = blockIdx.x;
  const int t  = threadIdx.x;

  const float* in; unsigned short* out;
  int in_ld, out_ld, ri, ci;
  if (blockIdx.z == 0) {
    in  = kin + (size_t)bh * D_HEAD * S_LEN;   // [64][2048]
    out = kT  + (size_t)bh * S_LEN * D_HEAD;   // [2048][64]
    in_ld = S_LEN; out_ld = D_HEAD; ri = 0; ci = bx * 64;
  } else {
    in  = vin + (size_t)bh * S_LEN * D_HEAD;   // [2048][64]
    out = vT  + (size_t)bh * D_HEAD * S_LEN;   // [64][2048]
    in_ld = D_HEAD; out_ld = S_LEN; ri = bx * 64; ci = 0;
  }

  {
    const int r  = t >> 2;            // 0..63
    const int c4 = (t & 3) * 16;      // 0/16/32/48
    const float* src = in + (size_t)(ri + r) * in_ld + ci + c4;
    #pragma unroll
    for (int i = 0; i < 4; ++i) {
      float4 f = *reinterpret_cast<const float4*>(src + i * 4);
      tile[r][c4 + i*4 + 0] = f.x;
      tile[r][c4 + i*4 + 1] = f.y;
      tile[r][c4 + i*4 + 2] = f.z;
      tile[r][c4 + i*4 + 3] = f.w;
    }
  }
  __syncthreads();
  {
    const int c  = t >> 2;
    const int r4 = (t & 3) * 16;
    union { unsigned short h[16]; uint4 q[2]; } u;
    #pragma unroll
    for (int i = 0; i < 16; ++i) u.h[i] = (unsigned short)f2bf(tile[r4 + i][c]);
    uint4* dst = reinterpret_cast<uint4*>(out + (size_t)(ci + c) * out_ld + ri + r4);
    dst[0] = u.q[0];
    dst[1] = u.q[1];
  }
}

// ---------------------------------------------------------------------------
// Kernel A: scores = (Q @ K) * scale + prev  (written f32), plus online
// row max m and row sum-of-exp l written to ws.
// Block = 64 rows of one bh; 4 waves x 16 rows each; loop 32 col-tiles of 64.
// MFMA 16x16x32 bf16. C layout (verified): col=lane&15, row=(lane>>4)*4+reg.
// A/B frag k-mapping: k = (lane>>4)*8 + j on BOTH operands (consistent ->
// internal k-permutation cancels).
// ---------------------------------------------------------------------------
__global__ __launch_bounds__(256) void scores_kernel(
    const float* __restrict__ q, const unsigned short* __restrict__ kT,
    const float* __restrict__ prev, const float* __restrict__ scale_p,
    float* __restrict__ scores, float* __restrict__ ws_m, float* __restrict__ ws_l)
{
  const int bh   = blockIdx.y;
  const int m0   = blockIdx.x * 64;
  const int tid  = threadIdx.x;
  const int w    = tid >> 6;
  const int lane = tid & 63;
  const int lg   = lane >> 4;   // 0..3  (k-octet group / C row group)
  const int lr   = lane & 15;   // A row within tile / C col within tile
  const float scale = scale_p[0];
  const int mw = m0 + w * 16;

  // Q fragments (resident across all col tiles): row = mw+lr, d = kk*32+lg*8+j
  short8 aq[2];
  const float* qrow = q + ((size_t)bh * S_LEN + (mw + lr)) * D_HEAD;
  #pragma unroll
  for (int kk = 0; kk < 2; ++kk) {
    float4 f0 = *reinterpret_cast<const float4*>(qrow + kk*32 + lg*8);
    float4 f1 = *reinterpret_cast<const float4*>(qrow + kk*32 + lg*8 + 4);
    short8 a;
    a[0]=f2bf(f0.x); a[1]=f2bf(f0.y); a[2]=f2bf(f0.z); a[3]=f2bf(f0.w);
    a[4]=f2bf(f1.x); a[5]=f2bf(f1.y); a[6]=f2bf(f1.z); a[7]=f2bf(f1.w);
    aq[kk] = a;
  }

  float m_run[4] = {-INFINITY, -INFINITY, -INFINITY, -INFINITY};
  float l_run[4] = {0.f, 0.f, 0.f, 0.f};

  const unsigned short* kbase = kT + (size_t)bh * S_LEN * D_HEAD;
  const float* prow = prev   + (size_t)bh * S_LEN * S_LEN;
  float*       srow = scores + (size_t)bh * S_LEN * S_LEN;

  for (int n0 = 0; n0 < S_LEN; n0 += 64) {
    f32x4 acc[4];
    #pragma unroll
    for (int nt = 0; nt < 4; ++nt) acc[nt] = (f32x4){0.f, 0.f, 0.f, 0.f};

    #pragma unroll
    for (int kk = 0; kk < 2; ++kk) {
      #pragma unroll
      for (int nt = 0; nt < 4; ++nt) {
        const unsigned short* kp =
            kbase + (size_t)(n0 + nt*16 + lr) * D_HEAD + kk*32 + lg*8;
        short8 b = *reinterpret_cast<const short8*>(kp);
        acc[nt] = __builtin_amdgcn_mfma_f32_16x16x32_bf16(aq[kk], b, acc[nt], 0, 0, 0);
      }
    }

    // scale + prev, write scores, keep values for stats
    float s[4][4];
    #pragma unroll
    for (int nt = 0; nt < 4; ++nt) {
      const int col = n0 + nt*16 + lr;
      #pragma unroll
      for (int rg = 0; rg < 4; ++rg) {
        const int row = mw + lg*4 + rg;
        float val = acc[nt][rg] * scale + prow[(size_t)row * S_LEN + col];
        s[nt][rg] = val;
        srow[(size_t)row * S_LEN + col] = val;
      }
    }

    // online softmax stats; rows live in 16-lane groups (shfl masks <16 stay in-group)
    #pragma unroll
    for (int rg = 0; rg < 4; ++rg) {
      float tmax = fmaxf(fmaxf(s[0][rg], s[1][rg]), fmaxf(s[2][rg], s[3][rg]));
      #pragma unroll
      for (int msk = 8; msk >= 1; msk >>= 1)
        tmax = fmaxf(tmax, __shfl_xor(tmax, msk, 64));
      const float mnew = fmaxf(m_run[rg], tmax);
      float se = __expf(s[0][rg]-mnew) + __expf(s[1][rg]-mnew)
               + __expf(s[2][rg]-mnew) + __expf(s[3][rg]-mnew);
      #pragma unroll
      for (int msk = 8; msk >= 1; msk >>= 1)
        se += __shfl_xor(se, msk, 64);
      l_run[rg] = l_run[rg] * __expf(m_run[rg] - mnew) + se;
      m_run[rg] = mnew;
    }
  }

  #pragma unroll
  for (int rg = 0; rg < 4; ++rg) {
    if (lr == rg) {
      const int row = mw + lg*4 + rg;
      ws_m[bh * S_LEN + row] = m_run[rg];
      ws_l[bh * S_LEN + row] = l_run[rg];
    }
  }
}

// ---------------------------------------------------------------------------
// Kernel B: weights = exp(s - m) / l (written f32), O = weights @ V (bf16 MFMA).
// Each wave owns 16 rows, loops all 2048 cols in K-steps of 32. No LDS, no syncs.
// ---------------------------------------------------------------------------
__global__ __launch_bounds__(256) void pv_kernel(
    const float* __restrict__ scores, const unsigned short* __restrict__ vT,
    const float* __restrict__ ws_m, const float* __restrict__ ws_l,
    float* __restrict__ weights, float* __restrict__ outO)
{
  const int bh   = blockIdx.y;
  const int m0   = blockIdx.x * 64;
  const int tid  = threadIdx.x;
  const int w    = tid >> 6;
  const int lane = tid & 63;
  const int lg   = lane >> 4;
  const int lr   = lane & 15;

  const int mrow = m0 + w*16 + lr;           // A-frag row for this lane
  const float mr = ws_m[bh * S_LEN + mrow];
  const float rl = 1.0f / ws_l[bh * S_LEN + mrow];

  const float* srow = scores  + (size_t)bh * S_LEN * S_LEN + (size_t)mrow * S_LEN;
  float*       wrow = weights + (size_t)bh * S_LEN * S_LEN + (size_t)mrow * S_LEN;
  const unsigned short* vbase = vT + (size_t)bh * D_HEAD * S_LEN;

  f32x4 acc[4];
  #pragma unroll
  for (int nt = 0; nt < 4; ++nt) acc[nt] = (f32x4){0.f, 0.f, 0.f, 0.f};

  for (int n0 = 0; n0 < S_LEN; n0 += 32) {
    const int nb = n0 + lg*8;
    float4 f0 = *reinterpret_cast<const float4*>(srow + nb);
    float4 f1 = *reinterpret_cast<const float4*>(srow + nb + 4);

    float wv[8];
    wv[0] = __expf(f0.x - mr) * rl;  wv[1] = __expf(f0.y - mr) * rl;
    wv[2] = __expf(f0.z - mr) * rl;  wv[3] = __expf(f0.w - mr) * rl;
    wv[4] = __expf(f1.x - mr) * rl;  wv[5] = __expf(f1.y - mr) * rl;
    wv[6] = __expf(f1.z - mr) * rl;  wv[7] = __expf(f1.w - mr) * rl;

    *reinterpret_cast<float4*>(wrow + nb)     = make_float4(wv[0], wv[1], wv[2], wv[3]);
    *reinterpret_cast<float4*>(wrow + nb + 4) = make_float4(wv[4], wv[5], wv[6], wv[7]);

    short8 a;
    #pragma unroll
    for (int j = 0; j < 8; ++j) a[j] = f2bf(wv[j]);

    #pragma unroll
    for (int nt = 0; nt < 4; ++nt) {
      const unsigned short* vp = vbase + (size_t)(nt*16 + lr) * S_LEN + nb;
      short8 b = *reinterpret_cast<const short8*>(vp);
      acc[nt] = __builtin_amdgcn_mfma_f32_16x16x32_bf16(a, b, acc[nt], 0, 0, 0);
    }
  }

  // C layout: col = lane&15 (-> dc tile offset), row = (lane>>4)*4 + reg
  #pragma unroll
  for (int nt = 0; nt < 4; ++nt) {
    #pragma unroll
    for (int rg = 0; rg < 4; ++rg) {
      const int row = m0 + w*16 + lg*4 + rg;
      const int dc  = nt*16 + lr;
      outO[((size_t)bh * S_LEN + row) * D_HEAD + dc] = acc[nt][rg];
    }
  }
}

// ---------------------------------------------------------------------------
extern "C" void kernel_launch(void* const* d_in, const int* in_sizes, int n_in,
                              void* d_out, int out_size, void* d_ws, size_t ws_size,
                              hipStream_t stream)
{
  const float* q     = (const float*)d_in[0];
  const float* kin   = (const float*)d_in[1];
  const float* vin   = (const float*)d_in[2];
  const float* prev  = (const float*)d_in[3];
  const float* scale = (const float*)d_in[4];

  float* O  = (float*)d_out;                                  // [32][2048][64]
  float* W  = O + (size_t)BH * S_LEN * D_HEAD;                // [32][2048][2048]
  float* Sc = W + (size_t)BH * S_LEN * S_LEN;                 // [32][2048][2048]

  // ws layout: kT (8MB bf16) | vT (8MB bf16) | m (256KB) | l (256KB)  ~= 16.5MB
  unsigned short* kT = (unsigned short*)d_ws;
  unsigned short* vT = kT + (size_t)BH * S_LEN * D_HEAD;
  float* ws_m = (float*)(vT + (size_t)BH * S_LEN * D_HEAD);
  float* ws_l = ws_m + BH * S_LEN;

  dim3 tgrid(S_LEN / 64, BH, 2);
  hipLaunchKernelGGL(transpose_kernel, tgrid, dim3(256), 0, stream, kin, vin, kT, vT);

  dim3 grid(S_LEN / 64, BH);
  hipLaunchKernelGGL(scores_kernel, grid, dim3(256), 0, stream,
                     q, kT, prev, scale, Sc, ws_m, ws_l);
  hipLaunchKernelGGL(pv_kernel, grid, dim3(256), 0, stream,
                     Sc, vT, ws_m, ws_l, W, O);
}